// Round 2
// 186.424 us; speedup vs baseline: 1.0836x; 1.0836x over previous
//
#include <hip/hip_runtime.h>

#define TB 1024
#define NIMG 512
#define HW 28
#define NPIX 784
#define TT 8
#define NFC 100
#define NOUT 10
#define MAGIC 0x5C5C5C5Cu

// workspace layout: wT [3136][100] floats, then u32 ctrl[]:
//   ctrl[0..97]   = transpose-done flags (MAGIC when slice written)
//   ctrl[98..129] = fr_g[32] (float)
//   ctrl[130]     = done2 counter
//   ctrl[131]     = fr_ready flag
#define WT_FLOATS 313600
#define GLB_ADD(p, v) __hip_atomic_fetch_add((p), (v), __ATOMIC_RELAXED, __HIP_MEMORY_SCOPE_AGENT)

typedef float f4 __attribute__((ext_vector_type(4)));

// ---------------------------------------------------------------------------
// Single fused kernel. One block (1024 thr = 16 waves) per image; 2 blocks/CU
// -> 32 waves/CU (100% occupancy ceiling, was 50% at 512 thr).
// Blocks 0..97 also transpose 32 columns of w_fc1 into wT (flag-published);
// block 0 zeroes the global accumulators; last finished block computes reg_loss.
// Arithmetic order per output value is bit-identical to the 512-thread version:
//  - gather is the original position-per-unit body (784 units, one pass)
//  - FC1 keeps 8 window streams, each served by 2 waves (cols 0..63 / 64..99)
//    with the same per-column j-order adds.
__global__ __launch_bounds__(TB, 8)
void snn_main(const float* __restrict__ xg, const float* __restrict__ w_sconv,
              const float* __restrict__ w_conv, const float* __restrict__ w_fc1,
              const float* __restrict__ w_fc2, float* __restrict__ wT,
              float* __restrict__ out, unsigned int* __restrict__ ctrl)
{
    __shared__ float wc[2880];                  // row r=ci*9+k at wc[r*20], 16 co
    __shared__ unsigned char spanB[25600];      // mask_t[8][784]u16 + t2n; later prefixLDS
    __shared__ unsigned short rowOr[TT * HW];   // per (t,row) OR of masks
    __shared__ unsigned char tqA[3136];         // pooled first-spike t; later t3L
    __shared__ unsigned short slist[3136];      // windows sorted by t
    __shared__ float xst[NPIX];
    __shared__ float wsc[144];
    __shared__ int bcnt[9], bofs[9], bput[8];
    __shared__ int hist[32];                    // [layer*8 + t]
    __shared__ int lastflag;

    unsigned short* mask_t = (unsigned short*)spanB;        // [t*784 + pos]
    unsigned int* mask32 = (unsigned int*)spanB;            // u32 view for atomicOr
    unsigned int* t2n = (unsigned int*)(spanB + 12544);     // [pos*2+w]: 16co x 4b
    float* prefixLDS = (float*)spanB;                       // [stream][t][neuron]

    unsigned int* tflags = ctrl;
    float* fr_g = (float*)(ctrl + 98);
    unsigned int* done2 = ctrl + 130;
    unsigned int* fr_ready = ctrl + 131;

    const int tid = threadIdx.x;
    const int b = blockIdx.x;

    // ---- cooperative transpose (blocks 0..97) + block-0 accumulator zeroing
    if (b < 98) {
        const int c0 = b * 32;
        for (int idx = tid; idx < 3200; idx += TB) {
            int c = idx / 100, r = idx - 100 * c;
            wT[(c0 + c) * 100 + r] = w_fc1[r * 3136 + c0 + c];
        }
    }
    if (b == 0 && tid < 33) ctrl[98 + tid] = 0u;   // fr_g[32] + done2

    // ---- stage
    for (int i = tid; i < NPIX; i += TB) xst[i] = xg[b * NPIX + i];
    for (int i = tid; i < 144; i += TB) wsc[i] = w_sconv[i];
    for (int i = tid; i < 2304; i += TB) {
        int c = i & 15, r = i >> 4;             // r = ci*9 + k, c = co
        wc[r * 20 + c] = w_conv[c * 144 + r];
    }
    for (int i = tid; i < 3136; i += TB) mask32[i] = 0u;    // 8*784 u16
    if (tid < 32) hist[tid] = 0;
    if (tid < 9) bcnt[tid] = 0;
    if (b < 98) __threadfence();                // publish wT/ctrl writes
    __syncthreads();
    if (b < 98 && tid == 0) {
        __hip_atomic_store(&tflags[b], MAGIC, __ATOMIC_RELEASE, __HIP_MEMORY_SCOPE_AGENT);
        if (b == 0)
            __hip_atomic_store(fr_ready, MAGIC, __ATOMIC_RELEASE, __HIP_MEMORY_SCOPE_AGENT);
    }

    // ---- phase A: xs conv + closed-form t1 -> mask bits
    unsigned int pca = 0, pcb = 0;
#pragma unroll 1
    for (int e = 0; e < 13; e++) {
        int g = e * TB + tid;
        if (g < 12544) {
            int ci = g & 15, pos = g >> 4;
            int yy = pos / HW, xx = pos % HW;
            float acc = 0.f;
#pragma unroll
            for (int ky = 0; ky < 3; ky++) {
                int ys = yy + ky - 1;
                if (ys < 0 || ys >= HW) continue;
#pragma unroll
                for (int kx = 0; kx < 3; kx++) {
                    int xsrc = xx + kx - 1;
                    if (xsrc < 0 || xsrc >= HW) continue;
                    acc = fmaf(wsc[ci * 9 + ky * 3 + kx], xst[ys * HW + xsrc], acc);
                }
            }
            int t1 = 8; float v = 0.f;
#pragma unroll
            for (int t = 0; t < TT; t++) {      // exact reference add order
                v += acc;
                if (t1 == 8 && v >= 1.0f) t1 = t;
            }
            if (t1 < 8) {
                int lin = t1 * NPIX + pos;
                atomicOr(&mask32[lin >> 1], (1u << ci) << ((lin & 1) * 16));
                if (t1 < 4) pca += 1u << (t1 * 8); else pcb += 1u << ((t1 - 4) * 8);
            }
        }
    }
#pragma unroll
    for (int t = 0; t < TT; t++) {
        unsigned int c = ((t < 4 ? (pca >> (t * 8)) : (pcb >> ((t - 4) * 8))) & 255u);
        if (c) atomicAdd(&hist[t], (int)c);
    }
    __syncthreads();

    // ---- row-union summary (skip table)
    for (int i = tid; i < TT * HW; i += TB) {   // i = t*28 + y
        const unsigned short* mr = mask_t + (i / HW) * NPIX + (i % HW) * HW;
        unsigned int o = 0;
#pragma unroll
        for (int x = 0; x < HW; x++) o |= mr[x];
        rowOr[i] = (unsigned short)o;
    }
    __syncthreads();

    // ---- gather: per-thread positions, v2[16] in packed f4 regs, LDS masks
    // (original position-per-unit body; 784 units fit in one 1024-thread pass)
    unsigned int pc2a = 0, pc2b = 0;
    {
        int pos = tid;
        if (pos < NPIX) {
            int py = pos / HW, px = pos - py * HW;
            f4 vv0 = {0.f, 0.f, 0.f, 0.f}, vv1 = vv0, vv2 = vv0, vv3 = vv0;
            unsigned int done = 0;
            unsigned int t2lo = 0x88888888u, t2hi = 0x88888888u;
#pragma unroll 1
            for (int t = 0; t < TT; t++) {
                const unsigned short* ro = rowOr + t * HW;
                unsigned int un = ro[py];
                if (py > 0) un |= ro[py - 1];
                if (py < HW - 1) un |= ro[py + 1];
                if (!un) continue;              // no adds at t -> no new crossing
                const unsigned short* mt = mask_t + t * NPIX;
#pragma unroll
                for (int k = 0; k < 9; k++) {
                    int qy = py + k / 3 - 1, qx = px + k % 3 - 1;
                    if ((unsigned)qy >= HW || (unsigned)qx >= HW) continue;
                    unsigned int m = mt[qy * HW + qx];
                    while (m) {
                        int ci = __builtin_ctz(m); m &= m - 1;
                        const f4* wrow = (const f4*)&wc[(ci * 9 + k) * 20];
                        vv0 += wrow[0]; vv1 += wrow[1];
                        vv2 += wrow[2]; vv3 += wrow[3];
                    }
                }
                unsigned int fired = 0;
#pragma unroll
                for (int c = 0; c < 16; c++) {
                    float val = (c < 4) ? vv0[c & 3] : (c < 8) ? vv1[c & 3]
                              : (c < 12) ? vv2[c & 3] : vv3[c & 3];
                    fired |= (val >= 1.0f) ? (1u << c) : 0u;
                }
                unsigned int newf = fired & ~done;
                done |= newf;
                if (newf) {
                    int cnt = __builtin_popcount(newf);
                    if (t < 4) pc2a += (unsigned)cnt << (t * 8);
                    else       pc2b += (unsigned)cnt << ((t - 4) * 8);
                    while (newf) {
                        int c = __builtin_ctz(newf); newf &= newf - 1;
                        if (c < 8) t2lo = (t2lo & ~(15u << (4 * c))) | ((unsigned)t << (4 * c));
                        else       t2hi = (t2hi & ~(15u << (4 * (c - 8)))) | ((unsigned)t << (4 * (c - 8)));
                    }
                }
                if (done == 0xffffu) break;     // all co fired; rest irrelevant
            }
            t2n[pos * 2] = t2lo;
            t2n[pos * 2 + 1] = t2hi;
        }
    }
#pragma unroll
    for (int t = 0; t < TT; t++) {
        unsigned int c = ((t < 4 ? (pc2a >> (t * 8)) : (pc2b >> ((t - 4) * 8))) & 255u);
        if (c) atomicAdd(&hist[8 + t], (int)c);
    }
    __syncthreads();

    // ---- first-spike pool + bucket histogram
    for (int u = tid; u < 3136; u += TB) {      // u = c*196 + wy*14 + wx
        int c = u / 196, rem = u - c * 196;
        int wy = rem / 14, wx = rem - wy * 14;
        int p0 = wy * 56 + wx * 2;
        int wsel = c >> 3, sh = (c & 7) * 4;
        int m0 = (t2n[p0 * 2 + wsel] >> sh) & 15;
        int m1 = (t2n[(p0 + 1) * 2 + wsel] >> sh) & 15;
        int m2 = (t2n[(p0 + HW) * 2 + wsel] >> sh) & 15;
        int m3 = (t2n[(p0 + HW + 1) * 2 + wsel] >> sh) & 15;
        int tqv = min(min(m0, m1), min(m2, m3));
        tqA[u] = (unsigned char)tqv;
        if (tqv < 8) atomicAdd(&bcnt[tqv], 1);
    }
    __syncthreads();
    if (tid == 0) {
        int s = 0;
#pragma unroll
        for (int t = 0; t < TT; t++) { bofs[t] = s; s += bcnt[t]; }
        bofs[8] = s;
    }
    __syncthreads();
    if (tid < 8) bput[tid] = bofs[tid];
    __syncthreads();
    for (int u = tid; u < 3136; u += TB) {
        int tqv = tqA[u];
        if (tqv < 8) { int j = atomicAdd(&bput[tqv], 1); slist[j] = (unsigned short)u; }
    }

    // ---- wait for wT slices (long since done; ~single pass)
    if (tid < 98) {
        while (__hip_atomic_load(&tflags[tid], __ATOMIC_ACQUIRE,
                                 __HIP_MEMORY_SCOPE_AGENT) != MAGIC)
            __builtin_amdgcn_s_sleep(2);
    }
    __syncthreads();                            // also covers t2n -> prefix reuse

    // ---- FC1 sorted-prefix scan: 8 streams x 2 waves (cols 0..63 / 64..99)
    {
        const int lane = tid & 63;
        const int w = tid >> 7;                 // stream 0..7, windows j == w mod 8
        const int sub = (tid >> 6) & 1;         // column group
        const int col = sub * 64 + lane;        // 0..127; valid < 100
        const bool act = col < NFC;
        const float* wA = wT + col;
        float acc0 = 0.f;
#pragma unroll 1
        for (int t = 0; t < TT; t++) {
            const int lo = bofs[t];
            const int n = bofs[t + 1] - lo;
            int j = w;
            for (; j + 24 < n; j += 32) {
                int u0 = (int)slist[lo + j] * 100;
                int u1 = (int)slist[lo + j + 8] * 100;
                int u2 = (int)slist[lo + j + 16] * 100;
                int u3 = (int)slist[lo + j + 24] * 100;
                if (act) {
                    float a0 = wA[u0], a1 = wA[u1], a2 = wA[u2], a3 = wA[u3];
                    acc0 += a0; acc0 += a1; acc0 += a2; acc0 += a3;
                }
            }
            for (; j < n; j += 8) {
                int u0 = (int)slist[lo + j] * 100;
                if (act) acc0 += wA[u0];
            }
            if (act) prefixLDS[(w * TT + t) * NFC + col] = acc0;
        }
    }
    __syncthreads();

    // ---- t3 from combined stream prefixes
    if (tid < NFC) {
        int t3 = 8;
#pragma unroll
        for (int t = 0; t < TT; t++) {
            float v = 0.f;
#pragma unroll
            for (int w = 0; w < 8; w++) v += prefixLDS[(w * TT + t) * NFC + tid];
            if (t3 == 8 && v >= 1.0f) t3 = t;
        }
        tqA[tid] = (unsigned char)t3;           // reuse as t3L
        if (t3 < 8) atomicAdd(&hist[16 + t3], 1);
    }
    __syncthreads();

    // ---- FC2 buckets + readout IF sim + latency score
    if (tid < NOUT) {
        float acc8[TT] = {0.f, 0.f, 0.f, 0.f, 0.f, 0.f, 0.f, 0.f};
        for (int i = 0; i < NFC; i++) {
            float w = w_fc2[tid * NFC + i];
            int tv = tqA[i];
#pragma unroll
            for (int k = 0; k < TT; k++) acc8[k] += (tv == k) ? w : 0.f;
        }
        float vout = 0.f; int cnt = 0; float lat = 0.f;
#pragma unroll
        for (int t = 0; t < TT; t++) {
            vout += acc8[t];
            if (vout >= 1.0f) { vout = 0.f; cnt++; atomicAdd(&hist[24 + t], 1); }
            if (cnt >= 1) lat += 1.f;
        }
        out[b * NOUT + tid] = lat * 0.125f;
    }
    __syncthreads();

    // ---- wait for fr_g zeroing (block 0; long since done), flush histograms
    if (tid == 0) {
        while (__hip_atomic_load(fr_ready, __ATOMIC_ACQUIRE,
                                 __HIP_MEMORY_SCOPE_AGENT) != MAGIC)
            __builtin_amdgcn_s_sleep(2);
    }
    __syncthreads();
    if (tid < 32) {
        int h = hist[tid];
        if (h) GLB_ADD(&fr_g[(tid & 7) * 4 + (tid >> 3)], (float)h);
    }
    __syncthreads();

    // ---- last-block-done fused finalize
    if (tid == 0) {
        unsigned int old = __hip_atomic_fetch_add(done2, 1u, __ATOMIC_ACQ_REL,
                                                  __HIP_MEMORY_SCOPE_AGENT);
        lastflag = (old == (unsigned)(NIMG - 1));
    }
    __syncthreads();
    if (lastflag && tid == 0) {
        const float inv0 = 1.f / 6422528.f;     // B*16*28*28
        const float inv2 = 1.f / 51200.f;       // B*100
        const float inv3 = 1.f / 5120.f;        // B*10
        const float invs[4] = { inv0, inv0, inv2, inv3 };
        float reg = 0.f;
        for (int l = 0; l < 4; l++) {
            float mx = -INFINITY;
            for (int t = 0; t < TT; t++) {
                float v = __hip_atomic_load(&fr_g[t * 4 + l], __ATOMIC_RELAXED,
                                            __HIP_MEMORY_SCOPE_AGENT);
                mx = fmaxf(mx, v * invs[l]);
            }
            reg += mx;
        }
        out[NIMG * NOUT] = reg;
    }
}

// ---------------------------------------------------------------------------
extern "C" void kernel_launch(void* const* d_in, const int* in_sizes, int n_in,
                              void* d_out, int out_size, void* d_ws, size_t ws_size,
                              hipStream_t stream) {
    const float* x       = (const float*)d_in[0];
    const float* w_sconv = (const float*)d_in[1];
    const float* w_conv  = (const float*)d_in[2];
    const float* w_fc1   = (const float*)d_in[3];
    const float* w_fc2   = (const float*)d_in[4];
    float* out = (float*)d_out;

    float* wT          = (float*)d_ws;
    unsigned int* ctrl = (unsigned int*)(wT + WT_FLOATS);

    snn_main<<<NIMG, TB, 0, stream>>>(x, w_sconv, w_conv, w_fc1, w_fc2, wT,
                                      out, ctrl);
}

// Round 3
// 173.512 us; speedup vs baseline: 1.1642x; 1.0744x over previous
//
#include <hip/hip_runtime.h>

#define TB 1024
#define NIMG 512
#define HW 28
#define NPIX 784
#define TT 8
#define NFC 100
#define NOUT 10
#define MAGIC 0x5C5C5C5Cu

// workspace layout: wT [3136][100] floats, then u32 ctrl[]:
//   ctrl[0..97]   = transpose-done flags (MAGIC when slice written)
//   ctrl[98..129] = fr_g[32] (float)
//   ctrl[130]     = done2 counter
//   ctrl[131]     = fr_ready flag
#define WT_FLOATS 313600
#define GLB_ADD(p, v) __hip_atomic_fetch_add((p), (v), __ATOMIC_RELAXED, __HIP_MEMORY_SCOPE_AGENT)

typedef float f4 __attribute__((ext_vector_type(4)));

// butterfly sum of 4 packed-u16 counters across the 64-lane wave
__device__ __forceinline__ void wave_sum4(unsigned int& a, unsigned int& b,
                                          unsigned int& c, unsigned int& d) {
#pragma unroll
    for (int s = 1; s < 64; s <<= 1) {
        a += __shfl_xor(a, s);
        b += __shfl_xor(b, s);
        c += __shfl_xor(c, s);
        d += __shfl_xor(d, s);
    }
}

// ---------------------------------------------------------------------------
// Single fused kernel. One block (1024 thr = 16 waves) per image; 2 blocks/CU.
// Round-3 changes vs round-2: gather position scramble (runs of 16) for wave
// load balance; wave-reduced histogram atomics; ballot-aggregated bucket
// scatter; FC1 8-deep load unroll; FC2 parallel over 10 waves.
__global__ __launch_bounds__(TB, 8)
void snn_main(const float* __restrict__ xg, const float* __restrict__ w_sconv,
              const float* __restrict__ w_conv, const float* __restrict__ w_fc1,
              const float* __restrict__ w_fc2, float* __restrict__ wT,
              float* __restrict__ out, unsigned int* __restrict__ ctrl)
{
    __shared__ float wc[2880];                  // row r=ci*9+k at wc[r*20], 16 co
    __shared__ unsigned char spanB[25600];      // mask_t[8][784]u16 + t2n; later prefixLDS
    __shared__ unsigned short rowOr[TT * HW];   // per (t,row) OR of masks
    __shared__ unsigned char tqA[3136];         // pooled first-spike t; later t3L
    __shared__ unsigned short slist[3136];      // windows sorted by t
    __shared__ float xst[NPIX];
    __shared__ float wsc[144];
    __shared__ int bcnt[9], bofs[9], bput[8];
    __shared__ int hist[32];                    // [layer*8 + t]
    __shared__ int lastflag;

    unsigned short* mask_t = (unsigned short*)spanB;        // [t*784 + pos]
    unsigned int* mask32 = (unsigned int*)spanB;            // u32 view for atomicOr
    unsigned int* t2n = (unsigned int*)(spanB + 12544);     // [pos*2+w]: 16co x 4b
    float* prefixLDS = (float*)spanB;                       // [stream][t][neuron]

    unsigned int* tflags = ctrl;
    float* fr_g = (float*)(ctrl + 98);
    unsigned int* done2 = ctrl + 130;
    unsigned int* fr_ready = ctrl + 131;

    const int tid = threadIdx.x;
    const int b = blockIdx.x;
    const int lane = tid & 63;

    // ---- cooperative transpose (blocks 0..97) + block-0 accumulator zeroing
    if (b < 98) {
        const int c0 = b * 32;
        for (int idx = tid; idx < 3200; idx += TB) {
            int c = idx / 100, r = idx - 100 * c;
            wT[(c0 + c) * 100 + r] = w_fc1[r * 3136 + c0 + c];
        }
    }
    if (b == 0 && tid < 33) ctrl[98 + tid] = 0u;   // fr_g[32] + done2

    // ---- stage
    for (int i = tid; i < NPIX; i += TB) xst[i] = xg[b * NPIX + i];
    for (int i = tid; i < 144; i += TB) wsc[i] = w_sconv[i];
    for (int i = tid; i < 2304; i += TB) {
        int c = i & 15, r = i >> 4;             // r = ci*9 + k, c = co
        wc[r * 20 + c] = w_conv[c * 144 + r];
    }
    for (int i = tid; i < 3136; i += TB) mask32[i] = 0u;    // 8*784 u16
    if (tid < 32) hist[tid] = 0;
    if (tid < 9) bcnt[tid] = 0;
    if (b < 98) __threadfence();                // publish wT/ctrl writes
    __syncthreads();
    if (b < 98 && tid == 0) {
        __hip_atomic_store(&tflags[b], MAGIC, __ATOMIC_RELEASE, __HIP_MEMORY_SCOPE_AGENT);
        if (b == 0)
            __hip_atomic_store(fr_ready, MAGIC, __ATOMIC_RELEASE, __HIP_MEMORY_SCOPE_AGENT);
    }

    // ---- phase A: xs conv + closed-form t1 -> mask bits
    unsigned int pca = 0, pcb = 0;
#pragma unroll 1
    for (int e = 0; e < 13; e++) {
        int g = e * TB + tid;
        if (g < 12544) {
            int ci = g & 15, pos = g >> 4;
            int yy = pos / HW, xx = pos % HW;
            float acc = 0.f;
#pragma unroll
            for (int ky = 0; ky < 3; ky++) {
                int ys = yy + ky - 1;
                if (ys < 0 || ys >= HW) continue;
#pragma unroll
                for (int kx = 0; kx < 3; kx++) {
                    int xsrc = xx + kx - 1;
                    if (xsrc < 0 || xsrc >= HW) continue;
                    acc = fmaf(wsc[ci * 9 + ky * 3 + kx], xst[ys * HW + xsrc], acc);
                }
            }
            int t1 = 8; float v = 0.f;
#pragma unroll
            for (int t = 0; t < TT; t++) {      // exact reference add order
                v += acc;
                if (t1 == 8 && v >= 1.0f) t1 = t;
            }
            if (t1 < 8) {
                int lin = t1 * NPIX + pos;
                atomicOr(&mask32[lin >> 1], (1u << ci) << ((lin & 1) * 16));
                if (t1 < 4) pca += 1u << (t1 * 8); else pcb += 1u << ((t1 - 4) * 8);
            }
        }
    }
    {   // wave-reduced histogram flush (counts <=13/thread -> u16 fields safe)
        unsigned int a_lo = pca & 0x00ff00ffu, a_hi = (pca >> 8) & 0x00ff00ffu;
        unsigned int b_lo = pcb & 0x00ff00ffu, b_hi = (pcb >> 8) & 0x00ff00ffu;
        wave_sum4(a_lo, a_hi, b_lo, b_hi);
        if (lane == 0) {
            if (a_lo & 0xffffu)  atomicAdd(&hist[0], (int)(a_lo & 0xffffu));
            if (a_hi & 0xffffu)  atomicAdd(&hist[1], (int)(a_hi & 0xffffu));
            if (a_lo >> 16)      atomicAdd(&hist[2], (int)(a_lo >> 16));
            if (a_hi >> 16)      atomicAdd(&hist[3], (int)(a_hi >> 16));
            if (b_lo & 0xffffu)  atomicAdd(&hist[4], (int)(b_lo & 0xffffu));
            if (b_hi & 0xffffu)  atomicAdd(&hist[5], (int)(b_hi & 0xffffu));
            if (b_lo >> 16)      atomicAdd(&hist[6], (int)(b_lo >> 16));
            if (b_hi >> 16)      atomicAdd(&hist[7], (int)(b_hi >> 16));
        }
    }
    __syncthreads();

    // ---- row-union summary (skip table)
    for (int i = tid; i < TT * HW; i += TB) {   // i = t*28 + y
        const unsigned short* mr = mask_t + (i / HW) * NPIX + (i % HW) * HW;
        unsigned int o = 0;
#pragma unroll
        for (int x = 0; x < HW; x++) o |= mr[x];
        rowOr[i] = (unsigned short)o;
    }
    __syncthreads();

    // ---- gather: per-thread positions, v2[16] in packed f4 regs, LDS masks
    // Load balance: runs of 16 pixels permuted so each wave holds 4 scattered
    // patches (spike events cluster spatially; wave cost = worst lane).
    unsigned int pc2a = 0, pc2b = 0;
    {
        int run = tid >> 4;
        int pos = (run < 49) ? ((run * 18) % 49) * 16 + (tid & 15) : -1;
        if (pos >= 0) {
            int py = pos / HW, px = pos - py * HW;
            f4 vv0 = {0.f, 0.f, 0.f, 0.f}, vv1 = vv0, vv2 = vv0, vv3 = vv0;
            unsigned int done = 0;
            unsigned int t2lo = 0x88888888u, t2hi = 0x88888888u;
#pragma unroll 1
            for (int t = 0; t < TT; t++) {
                const unsigned short* ro = rowOr + t * HW;
                unsigned int un = ro[py];
                if (py > 0) un |= ro[py - 1];
                if (py < HW - 1) un |= ro[py + 1];
                if (!un) continue;              // no adds at t -> no new crossing
                const unsigned short* mt = mask_t + t * NPIX;
#pragma unroll
                for (int k = 0; k < 9; k++) {
                    int qy = py + k / 3 - 1, qx = px + k % 3 - 1;
                    if ((unsigned)qy >= HW || (unsigned)qx >= HW) continue;
                    unsigned int m = mt[qy * HW + qx];
                    while (m) {
                        int ci = __builtin_ctz(m); m &= m - 1;
                        const f4* wrow = (const f4*)&wc[(ci * 9 + k) * 20];
                        vv0 += wrow[0]; vv1 += wrow[1];
                        vv2 += wrow[2]; vv3 += wrow[3];
                    }
                }
                unsigned int fired = 0;
#pragma unroll
                for (int c = 0; c < 16; c++) {
                    float val = (c < 4) ? vv0[c & 3] : (c < 8) ? vv1[c & 3]
                              : (c < 12) ? vv2[c & 3] : vv3[c & 3];
                    fired |= (val >= 1.0f) ? (1u << c) : 0u;
                }
                unsigned int newf = fired & ~done;
                done |= newf;
                if (newf) {
                    int cnt = __builtin_popcount(newf);
                    if (t < 4) pc2a += (unsigned)cnt << (t * 8);
                    else       pc2b += (unsigned)cnt << ((t - 4) * 8);
                    while (newf) {
                        int c = __builtin_ctz(newf); newf &= newf - 1;
                        if (c < 8) t2lo = (t2lo & ~(15u << (4 * c))) | ((unsigned)t << (4 * c));
                        else       t2hi = (t2hi & ~(15u << (4 * (c - 8)))) | ((unsigned)t << (4 * (c - 8)));
                    }
                }
                if (done == 0xffffu) break;     // all co fired; rest irrelevant
            }
            t2n[pos * 2] = t2lo;
            t2n[pos * 2 + 1] = t2hi;
        }
    }
    {   // wave-reduced histogram flush (counts <=16/thread -> u16 fields safe)
        unsigned int a_lo = pc2a & 0x00ff00ffu, a_hi = (pc2a >> 8) & 0x00ff00ffu;
        unsigned int b_lo = pc2b & 0x00ff00ffu, b_hi = (pc2b >> 8) & 0x00ff00ffu;
        wave_sum4(a_lo, a_hi, b_lo, b_hi);
        if (lane == 0) {
            if (a_lo & 0xffffu)  atomicAdd(&hist[8],  (int)(a_lo & 0xffffu));
            if (a_hi & 0xffffu)  atomicAdd(&hist[9],  (int)(a_hi & 0xffffu));
            if (a_lo >> 16)      atomicAdd(&hist[10], (int)(a_lo >> 16));
            if (a_hi >> 16)      atomicAdd(&hist[11], (int)(a_hi >> 16));
            if (b_lo & 0xffffu)  atomicAdd(&hist[12], (int)(b_lo & 0xffffu));
            if (b_hi & 0xffffu)  atomicAdd(&hist[13], (int)(b_hi & 0xffffu));
            if (b_lo >> 16)      atomicAdd(&hist[14], (int)(b_lo >> 16));
            if (b_hi >> 16)      atomicAdd(&hist[15], (int)(b_hi >> 16));
        }
    }
    __syncthreads();

    // ---- first-spike pool + wave-reduced bucket histogram
    {
        unsigned int cpa = 0, cpb = 0;          // per-thread bucket counts (<=4)
        for (int u = tid; u < 3136; u += TB) {  // u = c*196 + wy*14 + wx
            int c = u / 196, rem = u - c * 196;
            int wy = rem / 14, wx = rem - wy * 14;
            int p0 = wy * 56 + wx * 2;
            int wsel = c >> 3, sh = (c & 7) * 4;
            int m0 = (t2n[p0 * 2 + wsel] >> sh) & 15;
            int m1 = (t2n[(p0 + 1) * 2 + wsel] >> sh) & 15;
            int m2 = (t2n[(p0 + HW) * 2 + wsel] >> sh) & 15;
            int m3 = (t2n[(p0 + HW + 1) * 2 + wsel] >> sh) & 15;
            int tqv = min(min(m0, m1), min(m2, m3));
            tqA[u] = (unsigned char)tqv;
            if (tqv < 8) {
                if (tqv < 4) cpa += 1u << (tqv * 8);
                else         cpb += 1u << ((tqv - 4) * 8);
            }
        }
        unsigned int a_lo = cpa & 0x00ff00ffu, a_hi = (cpa >> 8) & 0x00ff00ffu;
        unsigned int b_lo = cpb & 0x00ff00ffu, b_hi = (cpb >> 8) & 0x00ff00ffu;
        wave_sum4(a_lo, a_hi, b_lo, b_hi);
        if (lane == 0) {
            if (a_lo & 0xffffu)  atomicAdd(&bcnt[0], (int)(a_lo & 0xffffu));
            if (a_hi & 0xffffu)  atomicAdd(&bcnt[1], (int)(a_hi & 0xffffu));
            if (a_lo >> 16)      atomicAdd(&bcnt[2], (int)(a_lo >> 16));
            if (a_hi >> 16)      atomicAdd(&bcnt[3], (int)(a_hi >> 16));
            if (b_lo & 0xffffu)  atomicAdd(&bcnt[4], (int)(b_lo & 0xffffu));
            if (b_hi & 0xffffu)  atomicAdd(&bcnt[5], (int)(b_hi & 0xffffu));
            if (b_lo >> 16)      atomicAdd(&bcnt[6], (int)(b_lo >> 16));
            if (b_hi >> 16)      atomicAdd(&bcnt[7], (int)(b_hi >> 16));
        }
    }
    __syncthreads();
    if (tid == 0) {
        int s = 0;
#pragma unroll
        for (int t = 0; t < TT; t++) { bofs[t] = s; s += bcnt[t]; }
        bofs[8] = s;
    }
    __syncthreads();
    if (tid < 8) bput[tid] = bofs[tid];
    __syncthreads();
    // ---- ballot-aggregated scatter: one atomic per (wave,bucket)
    for (int base_u = 0; base_u < 3136; base_u += TB) {
        int u = base_u + tid;
        int tqv = (u < 3136) ? (int)tqA[u] : 8;
#pragma unroll 1
        for (int v = 0; v < TT; v++) {
            unsigned long long m = __ballot(tqv == v);
            if (!m) continue;                   // wave-uniform
            int lead = __ffsll((unsigned long long)m) - 1;
            int bs = 0;
            if (lane == lead) bs = atomicAdd(&bput[v], __popcll(m));
            bs = __shfl(bs, lead);
            if (tqv == v) {
                int rank = __popcll(m & ((1ull << lane) - 1ull));
                slist[bs + rank] = (unsigned short)u;
            }
        }
    }

    // ---- wait for wT slices (long since done; ~single pass)
    if (tid < 98) {
        while (__hip_atomic_load(&tflags[tid], __ATOMIC_ACQUIRE,
                                 __HIP_MEMORY_SCOPE_AGENT) != MAGIC)
            __builtin_amdgcn_s_sleep(2);
    }
    __syncthreads();                            // also covers t2n -> prefix reuse

    // ---- FC1 sorted-prefix scan: 8 streams x 2 waves (cols 0..63 / 64..99),
    //      8 loads in flight (per-column add order unchanged: ascending j)
    {
        const int w = tid >> 7;                 // stream 0..7, windows j == w mod 8
        const int sub = (tid >> 6) & 1;         // column group
        const int col = sub * 64 + lane;        // 0..127; valid < 100
        const bool act = col < NFC;
        const float* wA = wT + col;
        float acc0 = 0.f;
#pragma unroll 1
        for (int t = 0; t < TT; t++) {
            const int lo = bofs[t];
            const int n = bofs[t + 1] - lo;
            int j = w;
            for (; j + 56 < n; j += 64) {
                int u0 = (int)slist[lo + j] * 100;
                int u1 = (int)slist[lo + j + 8] * 100;
                int u2 = (int)slist[lo + j + 16] * 100;
                int u3 = (int)slist[lo + j + 24] * 100;
                int u4 = (int)slist[lo + j + 32] * 100;
                int u5 = (int)slist[lo + j + 40] * 100;
                int u6 = (int)slist[lo + j + 48] * 100;
                int u7 = (int)slist[lo + j + 56] * 100;
                if (act) {
                    float a0 = wA[u0], a1 = wA[u1], a2 = wA[u2], a3 = wA[u3];
                    float a4 = wA[u4], a5 = wA[u5], a6 = wA[u6], a7 = wA[u7];
                    acc0 += a0; acc0 += a1; acc0 += a2; acc0 += a3;
                    acc0 += a4; acc0 += a5; acc0 += a6; acc0 += a7;
                }
            }
            for (; j + 24 < n; j += 32) {
                int u0 = (int)slist[lo + j] * 100;
                int u1 = (int)slist[lo + j + 8] * 100;
                int u2 = (int)slist[lo + j + 16] * 100;
                int u3 = (int)slist[lo + j + 24] * 100;
                if (act) {
                    float a0 = wA[u0], a1 = wA[u1], a2 = wA[u2], a3 = wA[u3];
                    acc0 += a0; acc0 += a1; acc0 += a2; acc0 += a3;
                }
            }
            for (; j < n; j += 8) {
                int u0 = (int)slist[lo + j] * 100;
                if (act) acc0 += wA[u0];
            }
            if (act) prefixLDS[(w * TT + t) * NFC + col] = acc0;
        }
    }
    __syncthreads();

    // ---- t3 from combined stream prefixes
    if (tid < NFC) {
        int t3 = 8;
#pragma unroll
        for (int t = 0; t < TT; t++) {
            float v = 0.f;
#pragma unroll
            for (int w = 0; w < 8; w++) v += prefixLDS[(w * TT + t) * NFC + tid];
            if (t3 == 8 && v >= 1.0f) t3 = t;
        }
        tqA[tid] = (unsigned char)t3;           // reuse as t3L
        if (t3 < 8) atomicAdd(&hist[16 + t3], 1);
    }
    __syncthreads();

    // ---- FC2: 10 waves, lanes partial-sum acc8, butterfly-reduce, lane0 sim
    if (tid < 640) {
        const int o = tid >> 6;                 // output 0..9
        float acc8[TT] = {0.f, 0.f, 0.f, 0.f, 0.f, 0.f, 0.f, 0.f};
        {
            float wv = w_fc2[o * NFC + lane];
            int tv = tqA[lane];
#pragma unroll
            for (int k = 0; k < TT; k++) acc8[k] += (tv == k) ? wv : 0.f;
        }
        if (lane < 36) {
            float wv = w_fc2[o * NFC + 64 + lane];
            int tv = tqA[64 + lane];
#pragma unroll
            for (int k = 0; k < TT; k++) acc8[k] += (tv == k) ? wv : 0.f;
        }
#pragma unroll
        for (int s = 1; s < 64; s <<= 1) {
#pragma unroll
            for (int k = 0; k < TT; k++) acc8[k] += __shfl_xor(acc8[k], s);
        }
        if (lane == 0) {
            float vout = 0.f; int cnt = 0; float lat = 0.f;
#pragma unroll
            for (int t = 0; t < TT; t++) {
                vout += acc8[t];
                if (vout >= 1.0f) { vout = 0.f; cnt++; atomicAdd(&hist[24 + t], 1); }
                if (cnt >= 1) lat += 1.f;
            }
            out[b * NOUT + o] = lat * 0.125f;
        }
    }
    __syncthreads();

    // ---- wait for fr_g zeroing (block 0; long since done), flush histograms
    if (tid == 0) {
        while (__hip_atomic_load(fr_ready, __ATOMIC_ACQUIRE,
                                 __HIP_MEMORY_SCOPE_AGENT) != MAGIC)
            __builtin_amdgcn_s_sleep(2);
    }
    __syncthreads();
    if (tid < 32) {
        int h = hist[tid];
        if (h) GLB_ADD(&fr_g[(tid & 7) * 4 + (tid >> 3)], (float)h);
    }
    __syncthreads();

    // ---- last-block-done fused finalize
    if (tid == 0) {
        unsigned int old = __hip_atomic_fetch_add(done2, 1u, __ATOMIC_ACQ_REL,
                                                  __HIP_MEMORY_SCOPE_AGENT);
        lastflag = (old == (unsigned)(NIMG - 1));
    }
    __syncthreads();
    if (lastflag && tid == 0) {
        const float inv0 = 1.f / 6422528.f;     // B*16*28*28
        const float inv2 = 1.f / 51200.f;       // B*100
        const float inv3 = 1.f / 5120.f;        // B*10
        const float invs[4] = { inv0, inv0, inv2, inv3 };
        float reg = 0.f;
        for (int l = 0; l < 4; l++) {
            float mx = -INFINITY;
            for (int t = 0; t < TT; t++) {
                float v = __hip_atomic_load(&fr_g[t * 4 + l], __ATOMIC_RELAXED,
                                            __HIP_MEMORY_SCOPE_AGENT);
                mx = fmaxf(mx, v * invs[l]);
            }
            reg += mx;
        }
        out[NIMG * NOUT] = reg;
    }
}

// ---------------------------------------------------------------------------
extern "C" void kernel_launch(void* const* d_in, const int* in_sizes, int n_in,
                              void* d_out, int out_size, void* d_ws, size_t ws_size,
                              hipStream_t stream) {
    const float* x       = (const float*)d_in[0];
    const float* w_sconv = (const float*)d_in[1];
    const float* w_conv  = (const float*)d_in[2];
    const float* w_fc1   = (const float*)d_in[3];
    const float* w_fc2   = (const float*)d_in[4];
    float* out = (float*)d_out;

    float* wT          = (float*)d_ws;
    unsigned int* ctrl = (unsigned int*)(wT + WT_FLOATS);

    snn_main<<<NIMG, TB, 0, stream>>>(x, w_sconv, w_conv, w_fc1, w_fc2, wT,
                                      out, ctrl);
}